// Round 1
// baseline (59.471 us; speedup 1.0000x reference)
//
#include <hip/hip_runtime.h>
#include <math.h>

constexpr int Bn = 1024, Vn = 5023;
constexpr int NB = 32;        // batches per block in the main kernel
constexpr int PARAM_STRIDE = 96;  // 36 pose_feat + 5*12 A per batch

// ---------------------------------------------------------------------------
// Kernel A: per-batch pose math. 1 thread per batch.
// params layout per batch: [0..35] pose_feat (joint-1..4, row-major 3x3 - I),
//                          [36..95] A_j as 3x4 row-major, j=0..4
// ---------------------------------------------------------------------------

__device__ inline void rodrigues3(float rx, float ry, float rz, float R[9]) {
    const float eps = 1e-8f;
    float ax = rx + eps, ay = ry + eps, az = rz + eps;
    float ang = sqrtf(ax * ax + ay * ay + az * az);
    float inv = 1.0f / ang;
    float dx = rx * inv, dy = ry * inv, dz = rz * inv;
    float s = sinf(ang), c = cosf(ang), omc = 1.0f - c;
    float K[9] = {0.f, -dz, dy, dz, 0.f, -dx, -dy, dx, 0.f};
    float K2[9];
#pragma unroll
    for (int r = 0; r < 3; r++)
#pragma unroll
        for (int k = 0; k < 3; k++) {
            float acc = 0.f;
#pragma unroll
            for (int i = 0; i < 3; i++) acc += K[r * 3 + i] * K[i * 3 + k];
            K2[r * 3 + k] = acc;
        }
#pragma unroll
    for (int i = 0; i < 9; i++) R[i] = s * K[i] + omc * K2[i];
    R[0] += 1.f; R[4] += 1.f; R[8] += 1.f;
}

__device__ inline void rot6d(const float* x, float R[9]) {
    float a1x = x[0], a1y = x[1], a1z = x[2];
    float a2x = x[3], a2y = x[4], a2z = x[5];
    float n1 = sqrtf(a1x * a1x + a1y * a1y + a1z * a1z);
    float b1x = a1x / n1, b1y = a1y / n1, b1z = a1z / n1;
    float d = b1x * a2x + b1y * a2y + b1z * a2z;
    float tx = a2x - d * b1x, ty = a2y - d * b1y, tz = a2z - d * b1z;
    float n2 = sqrtf(tx * tx + ty * ty + tz * tz);
    float b2x = tx / n2, b2y = ty / n2, b2z = tz / n2;
    float b3x = b1y * b2z - b1z * b2y;
    float b3y = b1z * b2x - b1x * b2z;
    float b3z = b1x * b2y - b1y * b2x;
    R[0] = b1x; R[1] = b1y; R[2] = b1z;
    R[3] = b2x; R[4] = b2y; R[5] = b2z;
    R[6] = b3x; R[7] = b3y; R[8] = b3z;
}

// chain_out = chain_par @ [Ri|ti]
__device__ inline void compose(const float* Rp, const float* tp,
                               const float* Ri, const float* ti,
                               float* Ro, float* to) {
#pragma unroll
    for (int r = 0; r < 3; r++) {
#pragma unroll
        for (int c = 0; c < 3; c++) {
            Ro[r * 3 + c] = Rp[r * 3 + 0] * Ri[0 * 3 + c] +
                            Rp[r * 3 + 1] * Ri[1 * 3 + c] +
                            Rp[r * 3 + 2] * Ri[2 * 3 + c];
        }
        to[r] = Rp[r * 3 + 0] * ti[0] + Rp[r * 3 + 1] * ti[1] +
                Rp[r * 3 + 2] * ti[2] + tp[r];
    }
}

__global__ void flame_params_kernel(const float* __restrict__ g6,
                                    const float* __restrict__ neck,
                                    const float* __restrict__ jaw,
                                    const float* __restrict__ eye,
                                    const float* __restrict__ jrest,
                                    float* __restrict__ params) {
    int b = blockIdx.x * blockDim.x + threadIdx.x;
    if (b >= Bn) return;

    float R[5][9];
    rot6d(g6 + b * 6, R[0]);
    rodrigues3(neck[b * 3 + 0], neck[b * 3 + 1], neck[b * 3 + 2], R[1]);
    rodrigues3(jaw[b * 3 + 0], jaw[b * 3 + 1], jaw[b * 3 + 2], R[2]);
    rodrigues3(eye[b * 6 + 0], eye[b * 6 + 1], eye[b * 6 + 2], R[3]);
    rodrigues3(eye[b * 6 + 3], eye[b * 6 + 4], eye[b * 6 + 5], R[4]);

    float j[5][3];
#pragma unroll
    for (int i = 0; i < 5; i++) {
        j[i][0] = jrest[b * 15 + i * 3 + 0];
        j[i][1] = jrest[b * 15 + i * 3 + 1];
        j[i][2] = jrest[b * 15 + i * 3 + 2];
    }
    // relative joints: parents = [0,0,1,1,1]
    float rel[5][3];
#pragma unroll
    for (int c = 0; c < 3; c++) {
        rel[0][c] = j[0][c];
        rel[1][c] = j[1][c] - j[0][c];
        rel[2][c] = j[2][c] - j[1][c];
        rel[3][c] = j[3][c] - j[1][c];
        rel[4][c] = j[4][c] - j[1][c];
    }

    float CR[5][9], CT[5][3];
#pragma unroll
    for (int i = 0; i < 9; i++) CR[0][i] = R[0][i];
#pragma unroll
    for (int c = 0; c < 3; c++) CT[0][c] = rel[0][c];
    compose(CR[0], CT[0], R[1], rel[1], CR[1], CT[1]);
    compose(CR[1], CT[1], R[2], rel[2], CR[2], CT[2]);
    compose(CR[1], CT[1], R[3], rel[3], CR[3], CT[3]);
    compose(CR[1], CT[1], R[4], rel[4], CR[4], CT[4]);

    float* P = params + b * PARAM_STRIDE;
    // pose_feat = (local rot mats 1..4) - I, row-major
#pragma unroll
    for (int jj = 0; jj < 4; jj++)
#pragma unroll
        for (int r = 0; r < 3; r++)
#pragma unroll
            for (int c = 0; c < 3; c++)
                P[jj * 9 + r * 3 + c] = R[jj + 1][r * 3 + c] - (r == c ? 1.f : 0.f);
    // A_j = [CR_j | CT_j - CR_j @ j_j] as 3x4 row-major
#pragma unroll
    for (int i = 0; i < 5; i++) {
#pragma unroll
        for (int r = 0; r < 3; r++) {
            float t = CT[i][r] - (CR[i][r * 3 + 0] * j[i][0] +
                                  CR[i][r * 3 + 1] * j[i][1] +
                                  CR[i][r * 3 + 2] * j[i][2]);
            P[36 + i * 12 + r * 4 + 0] = CR[i][r * 3 + 0];
            P[36 + i * 12 + r * 4 + 1] = CR[i][r * 3 + 1];
            P[36 + i * 12 + r * 4 + 2] = CR[i][r * 3 + 2];
            P[36 + i * 12 + r * 4 + 3] = t;
        }
    }
}

// ---------------------------------------------------------------------------
// Kernel B: per-vertex pose blendshapes + LBS. One thread per vertex,
// posedirs row (108 f32) + 5 lbs weights held in registers, loop over NB
// batches. Per-batch params read via wave-uniform address -> s_load.
// ---------------------------------------------------------------------------
__global__ __launch_bounds__(256) void flame_main_kernel(
    const float* __restrict__ vsh, const float* __restrict__ lbs,
    const float* __restrict__ pdirs, const float* __restrict__ params,
    float* __restrict__ out) {
    int v = blockIdx.x * 256 + threadIdx.x;
    bool valid = v < Vn;
    int vc = valid ? v : (Vn - 1);

    float pd[108];
#pragma unroll
    for (int i = 0; i < 27; i++) {
        float4 t = *reinterpret_cast<const float4*>(pdirs + (size_t)vc * 108 + i * 4);
        pd[i * 4 + 0] = t.x;
        pd[i * 4 + 1] = t.y;
        pd[i * 4 + 2] = t.z;
        pd[i * 4 + 3] = t.w;
    }
    float w[5];
#pragma unroll
    for (int jj = 0; jj < 5; jj++) w[jj] = lbs[(size_t)vc * 5 + jj];

    int b0 = blockIdx.y * NB;
    for (int bi = 0; bi < NB; bi++) {
        int b = b0 + bi;
        const float* __restrict__ P = params + b * PARAM_STRIDE;

        float ax = 0.f, ay = 0.f, az = 0.f;
#pragma unroll
        for (int p = 0; p < 36; p++) {
            float f = P[p];  // wave-uniform -> s_load
            ax = fmaf(f, pd[p * 3 + 0], ax);
            ay = fmaf(f, pd[p * 3 + 1], ay);
            az = fmaf(f, pd[p * 3 + 2], az);
        }

        size_t base = ((size_t)b * Vn + vc) * 3;
        float x = vsh[base + 0] + ax;
        float y = vsh[base + 1] + ay;
        float z = vsh[base + 2] + az;

        float ox = 0.f, oy = 0.f, oz = 0.f;
#pragma unroll
        for (int jj = 0; jj < 5; jj++) {
            const float* Aj = P + 36 + jj * 12;  // wave-uniform -> s_load
            float wj = w[jj];
            float rx = fmaf(Aj[0], x, fmaf(Aj[1], y, fmaf(Aj[2], z, Aj[3])));
            float ry = fmaf(Aj[4], x, fmaf(Aj[5], y, fmaf(Aj[6], z, Aj[7])));
            float rz = fmaf(Aj[8], x, fmaf(Aj[9], y, fmaf(Aj[10], z, Aj[11])));
            ox = fmaf(wj, rx, ox);
            oy = fmaf(wj, ry, oy);
            oz = fmaf(wj, rz, oz);
        }
        if (valid) {
            out[base + 0] = ox;
            out[base + 1] = oy;
            out[base + 2] = oz;
        }
    }
}

extern "C" void kernel_launch(void* const* d_in, const int* in_sizes, int n_in,
                              void* d_out, int out_size, void* d_ws, size_t ws_size,
                              hipStream_t stream) {
    const float* vsh   = (const float*)d_in[0];
    const float* g6    = (const float*)d_in[1];
    const float* neck  = (const float*)d_in[2];
    const float* jaw   = (const float*)d_in[3];
    const float* eye   = (const float*)d_in[4];
    const float* jrest = (const float*)d_in[5];
    const float* lbs   = (const float*)d_in[6];
    const float* pdirs = (const float*)d_in[7];
    float* out = (float*)d_out;
    float* params = (float*)d_ws;  // Bn * 96 floats = 384 KB

    hipLaunchKernelGGL(flame_params_kernel, dim3((Bn + 255) / 256), dim3(256), 0,
                       stream, g6, neck, jaw, eye, jrest, params);

    dim3 grid((Vn + 255) / 256, Bn / NB);
    hipLaunchKernelGGL(flame_main_kernel, grid, dim3(256), 0, stream, vsh, lbs,
                       pdirs, params, out);
}